// Round 10
// baseline (326.588 us; speedup 1.0000x reference)
//
#include <hip/hip_runtime.h>
#include <math.h>

#define BATCH 2
#define SEQ 2048
#define NX 1024
#define NSTATE 1024
#define NHEAD 16
#define HDIM 64
#define QKV_LD (3*NSTATE)

typedef __attribute__((ext_vector_type(4))) float f32x4;
typedef __attribute__((ext_vector_type(8))) short bf16x8;

__device__ __forceinline__ unsigned short f2bf(float x) {
    unsigned int u = __float_as_uint(x);
    u = (u + 0x7FFFu + ((u >> 16) & 1u)) >> 16;
    return (unsigned short)u;
}

__device__ __forceinline__ unsigned int cvtpk_bf16(float a, float b) {
    unsigned int r;
    asm("v_cvt_pk_bf16_f32 %0, %1, %2" : "=v"(r) : "v"(a), "v"(b));
    return r;
}

#define GLL(src, dst) __builtin_amdgcn_global_load_lds( \
    (const __attribute__((address_space(1))) void*)(src), \
    (__attribute__((address_space(3))) void*)(dst), 16, 0, 0)

// Fused prep: [0,4096) cast x -> bf16; [4096,4864) transpose-cast w_c;
// [4864,5120) transpose-cast w_p.
__global__ __launch_bounds__(256) void prep_kernel(
    const float* __restrict__ x, const float* __restrict__ w_c,
    const float* __restrict__ w_p,
    unsigned short* __restrict__ xbf, unsigned short* __restrict__ wcT,
    unsigned short* __restrict__ wpT)
{
    const int bx = blockIdx.x;
    const int t = threadIdx.x;
    if (bx < 4096) {
        int i = bx * 256 + t;
        float4 v = ((const float4*)x)[i];
        ushort4 o;
        o.x = f2bf(v.x); o.y = f2bf(v.y); o.z = f2bf(v.z); o.w = f2bf(v.w);
        ((ushort4*)xbf)[i] = o;
        return;
    }
    __shared__ float tile[64][65];
    const float* in;
    unsigned short* out;
    int R, C, c0, r0;
    if (bx < 4096 + 768) {
        int idx = bx - 4096;
        in = w_c; out = wcT; R = NX; C = 3 * NSTATE;
        c0 = (idx % 48) * 64; r0 = (idx / 48) * 64;
    } else {
        int idx = bx - 4864;
        in = w_p; out = wpT; R = NX; C = NSTATE;
        c0 = (idx % 16) * 64; r0 = (idx / 16) * 64;
    }
    const int cc = t & 63;
    const int rb = t >> 6;
    #pragma unroll
    for (int i = 0; i < 16; i++) {
        int rr = rb + i * 4;
        tile[rr][cc] = in[(size_t)(r0 + rr) * C + c0 + cc];
    }
    __syncthreads();
    #pragma unroll
    for (int i = 0; i < 16; i++) {
        int rr = rb + i * 4;
        out[(size_t)(c0 + rr) * R + r0 + cc] = f2bf(tile[cc][rr]);
    }
}

// V-part of qkv (bf16) -> vt[(b*16+h)*64+d][s]  (bf16)
__global__ __launch_bounds__(256) void vtrans_kernel(
    const unsigned short* __restrict__ qkv, unsigned short* __restrict__ vt)
{
    __shared__ unsigned short t[64][72];
    const int s0 = blockIdx.x * 64;
    const int bh = blockIdx.y;
    const int b = bh >> 4, h = bh & 15;
    const int r = threadIdx.x >> 2;
    const int cg = (threadIdx.x & 3) * 16;
    const unsigned short* src = qkv + (size_t)(b * SEQ + s0 + r) * QKV_LD
                                + 2 * NSTATE + h * HDIM + cg;
    *(bf16x8*)&t[r][cg]     = *(const bf16x8*)src;
    *(bf16x8*)&t[r][cg + 8] = *(const bf16x8*)(src + 8);
    __syncthreads();
    unsigned short tmp[16];
    #pragma unroll
    for (int i = 0; i < 16; i++) tmp[i] = t[cg + i][r];
    unsigned short* dst = vt + (size_t)(bh * 64 + r) * SEQ + s0 + cg;
    *(bf16x8*)dst       = ((const bf16x8*)tmp)[0];
    *(bf16x8*)(dst + 8) = ((const bf16x8*)tmp)[1];
}

// C[M,N] = A[M,K](bf16) @ BT[N,K]^T(bf16) + bias; out fp32 or bf16.
template<bool BF16_OUT>
__global__ __launch_bounds__(256) void gemm_bf16(
    const unsigned short* __restrict__ A,
    const unsigned short* __restrict__ BT,
    const float* __restrict__ bias,
    void* __restrict__ Cv, int M, int N, int K)
{
    __shared__ unsigned short Als[128 * 32];
    __shared__ unsigned short Bls[128 * 32];
    const int tid = threadIdx.x;
    const int wave = tid >> 6, lane = tid & 63;
    const int bm = blockIdx.x * 128, bn = blockIdx.y * 128;
    const int wr = (wave >> 1) * 64, wc = (wave & 1) * 64;

    f32x4 acc[4][4];
    #pragma unroll
    for (int m = 0; m < 4; m++)
        #pragma unroll
        for (int n = 0; n < 4; n++)
            acc[m][n] = (f32x4){0.f, 0.f, 0.f, 0.f};

    const int arow = tid >> 2;
    const int ac8 = (tid & 3) * 8;
    char* alds0 = (char*)Als + wave * 1024;
    char* blds0 = (char*)Bls + wave * 1024;
    const int fr = lane & 15, kq = (lane >> 4) * 8;

    for (int k0 = 0; k0 < K; k0 += 32) {
        const unsigned short* ga0 = A  + (size_t)(bm + arow) * K + k0 + ac8;
        const unsigned short* gb0 = BT + (size_t)(bn + arow) * K + k0 + ac8;
        GLL(ga0, alds0);
        GLL(ga0 + (size_t)64 * K, alds0 + 4096);
        GLL(gb0, blds0);
        GLL(gb0 + (size_t)64 * K, blds0 + 4096);
        __syncthreads();

        bf16x8 af[4], bfr[4];
        #pragma unroll
        for (int m = 0; m < 4; m++)
            af[m] = *(const bf16x8*)&Als[(wr + m * 16 + fr) * 32 + kq];
        #pragma unroll
        for (int n = 0; n < 4; n++)
            bfr[n] = *(const bf16x8*)&Bls[(wc + n * 16 + fr) * 32 + kq];
        #pragma unroll
        for (int m = 0; m < 4; m++)
            #pragma unroll
            for (int n = 0; n < 4; n++)
                acc[m][n] = __builtin_amdgcn_mfma_f32_16x16x32_bf16(
                    af[m], bfr[n], acc[m][n], 0, 0, 0);
        __syncthreads();
    }

    const int cr = (lane >> 4) * 4;
    const int ccol = lane & 15;
    #pragma unroll
    for (int m = 0; m < 4; m++) {
        const int row = bm + wr + m * 16 + cr;
        #pragma unroll
        for (int n = 0; n < 4; n++) {
            const int col = bn + wc + n * 16 + ccol;
            const float bv = bias[col];
            #pragma unroll
            for (int j = 0; j < 4; j++) {
                float v = acc[m][n][j] + bv;
                if (BF16_OUT)
                    ((unsigned short*)Cv)[(size_t)(row + j) * N + col] = f2bf(v);
                else
                    ((float*)Cv)[(size_t)(row + j) * N + col] = v;
            }
        }
    }
}

// MFMA flash attention v9: 1 wave per block, 16 q-rows, NO barriers, NO LDS
// staging. K fragments direct from qkv (row-major, contiguous 16B/lane);
// V fragments direct from vt (L2-resident via XCD grouping). Only P goes
// through (wave-private) LDS. grid = 4096 flat blocks:
//   xcd = beta&7, r = beta>>3, g=(b,h) = xcd*4 + (r&3), s = r>>2,
//   chunk = s even ? s/2 : 127 - s/2   (long/short interleave for balance)
__global__ __launch_bounds__(64, 4) void attn_mfma(
    const unsigned short* __restrict__ qkv,
    const unsigned short* __restrict__ vt,
    unsigned short* __restrict__ a_out)
{
    const int beta = blockIdx.x;
    const int xcd = beta & 7;
    const int r = beta >> 3;
    const int g = xcd * 4 + (r & 3);       // b*16 + h
    const int s = r >> 2;                  // 0..127
    const int chunk = (s & 1) ? (127 - (s >> 1)) : (s >> 1);
    const int b = g >> 4, h = g & 15;
    const int lane = threadIdx.x;
    const int c = lane & 15, hh = lane >> 4;

    __shared__ unsigned short Pls[16 * 64];    // 2KB, wave-private

    const float Cc = 0.18033688f;              // 0.125 * log2(e)

    const int qtile = chunk >> 2;
    const int rowoff = (chunk & 3) * 16;
    const int nkt = qtile + 1;

    // Q fragments
    const unsigned short* qp = qkv + (size_t)(b * SEQ + chunk * 16 + c) * QKV_LD + h * HDIM;
    bf16x8 qf0 = *(const bf16x8*)(qp + hh * 8);
    bf16x8 qf1 = *(const bf16x8*)(qp + 32 + hh * 8);

    const unsigned short* kbase = qkv + (size_t)b * SEQ * QKV_LD + NSTATE + h * HDIM;
    const unsigned short* vbase = vt + (size_t)g * HDIM * SEQ;

    f32x4 acc_o[4];
    #pragma unroll
    for (int n = 0; n < 4; n++) acc_o[n] = (f32x4){0.f, 0.f, 0.f, 0.f};
    float m_run = -1e30f, l = 0.f;

    for (int kt = 0; kt < nkt; kt++) {
        // K fragments direct from qkv rows (A-operand, contiguous 16B/lane)
        bf16x8 kf[4][2];
        #pragma unroll
        for (int m = 0; m < 4; m++) {
            const unsigned short* kp = kbase + (size_t)(kt * 64 + m * 16 + c) * QKV_LD;
            kf[m][0] = *(const bf16x8*)(kp + hh * 8);
            kf[m][1] = *(const bf16x8*)(kp + 32 + hh * 8);
        }
        // V fragments direct from vt (B-operand)
        bf16x8 vf[4][2];
        #pragma unroll
        for (int n = 0; n < 4; n++) {
            const unsigned short* vp = vbase + (size_t)(n * 16 + c) * SEQ + kt * 64;
            vf[n][0] = *(const bf16x8*)(vp + hh * 8);
            vf[n][1] = *(const bf16x8*)(vp + 32 + hh * 8);
        }

        // QK^T (swapped): sacc[m] cols=q(c), rows=keys m*16 + hh*4 + j
        f32x4 sacc[4];
        __builtin_amdgcn_s_setprio(1);
        #pragma unroll
        for (int m = 0; m < 4; m++) {
            f32x4 z = (f32x4){0.f, 0.f, 0.f, 0.f};
            z = __builtin_amdgcn_mfma_f32_16x16x32_bf16(kf[m][0], qf0, z, 0, 0, 0);
            sacc[m] = __builtin_amdgcn_mfma_f32_16x16x32_bf16(kf[m][1], qf1, z, 0, 0, 0);
        }
        __builtin_amdgcn_s_setprio(0);

        // softmax on raw scores; scale folded into exp2 constant
        const bool diag = (kt == qtile);
        float sv_[16];
        #pragma unroll
        for (int m = 0; m < 4; m++)
            #pragma unroll
            for (int j = 0; j < 4; j++) {
                float sv = sacc[m][j];
                if (diag) {
                    int klocal = m * 16 + hh * 4 + j;
                    if (klocal > rowoff + c) sv = -1e30f;
                }
                sv_[m * 4 + j] = sv;
            }
        // tree max over 16
        float x0 = fmaxf(sv_[0], sv_[1]),  x1 = fmaxf(sv_[2], sv_[3]);
        float x2 = fmaxf(sv_[4], sv_[5]),  x3 = fmaxf(sv_[6], sv_[7]);
        float x4 = fmaxf(sv_[8], sv_[9]),  x5 = fmaxf(sv_[10], sv_[11]);
        float x6 = fmaxf(sv_[12], sv_[13]), x7 = fmaxf(sv_[14], sv_[15]);
        float y0 = fmaxf(x0, x1), y1 = fmaxf(x2, x3);
        float y2 = fmaxf(x4, x5), y3 = fmaxf(x6, x7);
        float pmax = fmaxf(fmaxf(y0, y1), fmaxf(y2, y3));
        pmax = fmaxf(pmax, __shfl_xor(pmax, 16));
        pmax = fmaxf(pmax, __shfl_xor(pmax, 32));

        // defer-max: rescale only if some row's max grew by > 64 raw (=8 scaled)
        if (!__all(pmax <= m_run + 64.0f)) {
            const float mnew = fmaxf(m_run, pmax);
            const float alpha = exp2f((m_run - mnew) * Cc);
            m_run = mnew;
            l *= alpha;
            const float a0 = __shfl(alpha, hh * 4 + 0);
            const float a1 = __shfl(alpha, hh * 4 + 1);
            const float a2 = __shfl(alpha, hh * 4 + 2);
            const float a3 = __shfl(alpha, hh * 4 + 3);
            #pragma unroll
            for (int n = 0; n < 4; n++) {
                acc_o[n][0] *= a0; acc_o[n][1] *= a1;
                acc_o[n][2] *= a2; acc_o[n][3] *= a3;
            }
        }
        const float mc = m_run * Cc;
        float p[16];
        #pragma unroll
        for (int i = 0; i < 16; i++)
            p[i] = exp2f(fmaf(sv_[i], Cc, -mc));
        // tree sum into l
        {
            float a0 = p[0] + p[1],  a1 = p[2] + p[3];
            float a2 = p[4] + p[5],  a3 = p[6] + p[7];
            float a4 = p[8] + p[9],  a5 = p[10] + p[11];
            float a6 = p[12] + p[13], a7 = p[14] + p[15];
            float b0 = a0 + a1, b1 = a2 + a3, b2 = a4 + a5, b3 = a6 + a7;
            l += (b0 + b1) + (b2 + b3);
        }

        // pack P -> bf16 via v_cvt_pk_bf16_f32, swizzled wave-private LDS
        {
            char* pb = (char*)Pls + c * 128;
            const int swp = (c & 7) << 4;
            #pragma unroll
            for (int m = 0; m < 4; m++) {
                uint2 u;
                u.x = cvtpk_bf16(p[m * 4 + 0], p[m * 4 + 1]);
                u.y = cvtpk_bf16(p[m * 4 + 2], p[m * 4 + 3]);
                *(uint2*)(pb + ((m * 32 + hh * 8) ^ swp)) = u;
            }
        }

        // PV: out[q][d], A = P (LDS), B = vf (regs)
        {
            const char* pb = (const char*)Pls + c * 128;
            const int swp = (c & 7) << 4;
            bf16x8 pf0 = *(const bf16x8*)(pb + ((hh * 16) ^ swp));
            bf16x8 pf1 = *(const bf16x8*)(pb + ((64 + hh * 16) ^ swp));
            __builtin_amdgcn_s_setprio(1);
            #pragma unroll
            for (int n = 0; n < 4; n++) {
                acc_o[n] = __builtin_amdgcn_mfma_f32_16x16x32_bf16(pf0, vf[n][0], acc_o[n], 0, 0, 0);
                acc_o[n] = __builtin_amdgcn_mfma_f32_16x16x32_bf16(pf1, vf[n][1], acc_o[n], 0, 0, 0);
            }
            __builtin_amdgcn_s_setprio(0);
        }
    }

    // final normalization + store
    l += __shfl_xor(l, 16);
    l += __shfl_xor(l, 32);
    const float linv = 1.f / l;
    const float li0 = __shfl(linv, hh * 4 + 0);
    const float li1 = __shfl(linv, hh * 4 + 1);
    const float li2 = __shfl(linv, hh * 4 + 2);
    const float li3 = __shfl(linv, hh * 4 + 3);
    const size_t orow0 = (size_t)(b * SEQ + chunk * 16 + hh * 4);
    #pragma unroll
    for (int n = 0; n < 4; n++) {
        const int col = h * HDIM + n * 16 + c;
        a_out[(orow0 + 0) * NSTATE + col] = f2bf(acc_o[n][0] * li0);
        a_out[(orow0 + 1) * NSTATE + col] = f2bf(acc_o[n][1] * li1);
        a_out[(orow0 + 2) * NSTATE + col] = f2bf(acc_o[n][2] * li2);
        a_out[(orow0 + 3) * NSTATE + col] = f2bf(acc_o[n][3] * li3);
    }
}

extern "C" void kernel_launch(void* const* d_in, const int* in_sizes, int n_in,
                              void* d_out, int out_size, void* d_ws, size_t ws_size,
                              hipStream_t stream)
{
    const float* x   = (const float*)d_in[0];
    const float* w_c = (const float*)d_in[1];
    const float* b_c = (const float*)d_in[2];
    const float* w_p = (const float*)d_in[3];
    const float* b_p = (const float*)d_in[4];
    float* out = (float*)d_out;

    const int M = BATCH * SEQ;   // 4096

    char* ws = (char*)d_ws;
    unsigned short* qkvbf = (unsigned short*)ws;                          // 25165824 B
    unsigned short* vt    = (unsigned short*)(ws + 25165824);             //  8388608 B
    unsigned short* xbf   = (unsigned short*)(ws + 25165824 + 8388608);   //  8388608 B (reused as attn_out)
    unsigned short* wcT   = (unsigned short*)(ws + 25165824 + 2*8388608); //  6291456 B
    unsigned short* wpT   = (unsigned short*)(ws + 25165824 + 2*8388608 + 6291456); // 2097152 B

    // fused prep: cast x + transpose-cast w_c, w_p
    prep_kernel<<<5120, 256, 0, stream>>>(x, w_c, w_p, xbf, wcT, wpT);

    // 1) QKV projection -> bf16 qkv
    gemm_bf16<true><<<dim3(M / 128, 3 * NSTATE / 128), 256, 0, stream>>>(
        xbf, wcT, b_c, qkvbf, M, 3 * NSTATE, NX);

    // 1b) transpose V -> vt
    vtrans_kernel<<<dim3(SEQ / 64, BATCH * NHEAD), 256, 0, stream>>>(qkvbf, vt);

    // 2) MFMA flash attention (1-wave blocks, barrier-free, XCD-grouped)
    attn_mfma<<<4096, 64, 0, stream>>>(qkvbf, vt, xbf);

    // 3) output projection -> fp32 d_out
    gemm_bf16<false><<<dim3(M / 128, NSTATE / 128), 256, 0, stream>>>(
        xbf, wpT, b_p, out, M, NSTATE, NX);
}

// Round 11
// 196.605 us; speedup vs baseline: 1.6611x; 1.6611x over previous
//
#include <hip/hip_runtime.h>
#include <math.h>

#define BATCH 2
#define SEQ 2048
#define NX 1024
#define NSTATE 1024
#define NHEAD 16
#define HDIM 64
#define QKV_LD (3*NSTATE)

typedef __attribute__((ext_vector_type(4))) float f32x4;
typedef __attribute__((ext_vector_type(8))) short bf16x8;

__device__ __forceinline__ unsigned short f2bf(float x) {
    unsigned int u = __float_as_uint(x);
    u = (u + 0x7FFFu + ((u >> 16) & 1u)) >> 16;
    return (unsigned short)u;
}

__device__ __forceinline__ unsigned int cvtpk_bf16(float a, float b) {
    unsigned int r;
    asm("v_cvt_pk_bf16_f32 %0, %1, %2" : "=v"(r) : "v"(a), "v"(b));
    return r;
}

#define GLL(src, dst) __builtin_amdgcn_global_load_lds( \
    (const __attribute__((address_space(1))) void*)(src), \
    (__attribute__((address_space(3))) void*)(dst), 16, 0, 0)

// Fused prep: [0,4096) cast x -> bf16; [4096,4864) transpose-cast w_c;
// [4864,5120) transpose-cast w_p.
__global__ __launch_bounds__(256) void prep_kernel(
    const float* __restrict__ x, const float* __restrict__ w_c,
    const float* __restrict__ w_p,
    unsigned short* __restrict__ xbf, unsigned short* __restrict__ wcT,
    unsigned short* __restrict__ wpT)
{
    const int bx = blockIdx.x;
    const int t = threadIdx.x;
    if (bx < 4096) {
        int i = bx * 256 + t;
        float4 v = ((const float4*)x)[i];
        ushort4 o;
        o.x = f2bf(v.x); o.y = f2bf(v.y); o.z = f2bf(v.z); o.w = f2bf(v.w);
        ((ushort4*)xbf)[i] = o;
        return;
    }
    __shared__ float tile[64][65];
    const float* in;
    unsigned short* out;
    int R, C, c0, r0;
    if (bx < 4096 + 768) {
        int idx = bx - 4096;
        in = w_c; out = wcT; R = NX; C = 3 * NSTATE;
        c0 = (idx % 48) * 64; r0 = (idx / 48) * 64;
    } else {
        int idx = bx - 4864;
        in = w_p; out = wpT; R = NX; C = NSTATE;
        c0 = (idx % 16) * 64; r0 = (idx / 16) * 64;
    }
    const int cc = t & 63;
    const int rb = t >> 6;
    #pragma unroll
    for (int i = 0; i < 16; i++) {
        int rr = rb + i * 4;
        tile[rr][cc] = in[(size_t)(r0 + rr) * C + c0 + cc];
    }
    __syncthreads();
    #pragma unroll
    for (int i = 0; i < 16; i++) {
        int rr = rb + i * 4;
        out[(size_t)(c0 + rr) * R + r0 + cc] = f2bf(tile[cc][rr]);
    }
}

// V-part of qkv (bf16) -> vt[(b*16+h)*64+d][s]  (bf16)
__global__ __launch_bounds__(256) void vtrans_kernel(
    const unsigned short* __restrict__ qkv, unsigned short* __restrict__ vt)
{
    __shared__ unsigned short t[64][72];
    const int s0 = blockIdx.x * 64;
    const int bh = blockIdx.y;
    const int b = bh >> 4, h = bh & 15;
    const int r = threadIdx.x >> 2;
    const int cg = (threadIdx.x & 3) * 16;
    const unsigned short* src = qkv + (size_t)(b * SEQ + s0 + r) * QKV_LD
                                + 2 * NSTATE + h * HDIM + cg;
    *(bf16x8*)&t[r][cg]     = *(const bf16x8*)src;
    *(bf16x8*)&t[r][cg + 8] = *(const bf16x8*)(src + 8);
    __syncthreads();
    unsigned short tmp[16];
    #pragma unroll
    for (int i = 0; i < 16; i++) tmp[i] = t[cg + i][r];
    unsigned short* dst = vt + (size_t)(bh * 64 + r) * SEQ + s0 + cg;
    *(bf16x8*)dst       = ((const bf16x8*)tmp)[0];
    *(bf16x8*)(dst + 8) = ((const bf16x8*)tmp)[1];
}

// C[M,N] = A[M,K](bf16) @ BT[N,K]^T(bf16) + bias. 128x128 tile, 1D grid with
// bijective XCD-region swizzle: xcd=flat&7 gets an RX x RY block region.
template<int RX, int RY, int NBX, bool BF16_OUT>
__global__ __launch_bounds__(256) void gemm_bf16(
    const unsigned short* __restrict__ A,
    const unsigned short* __restrict__ BT,
    const float* __restrict__ bias,
    void* __restrict__ Cv, int M, int N, int K)
{
    const int flat = blockIdx.x;
    const int xcd = flat & 7;
    const int j = flat >> 3;
    const int bx = (xcd % (NBX / RX)) * RX + (j % RX);
    const int by = (xcd / (NBX / RX)) * RY + (j / RX);

    __shared__ unsigned short Als[128 * 32];
    __shared__ unsigned short Bls[128 * 32];
    const int tid = threadIdx.x;
    const int wave = tid >> 6, lane = tid & 63;
    const int bm = bx * 128, bn = by * 128;
    const int wr = (wave >> 1) * 64, wc = (wave & 1) * 64;

    f32x4 acc[4][4];
    #pragma unroll
    for (int m = 0; m < 4; m++)
        #pragma unroll
        for (int n = 0; n < 4; n++)
            acc[m][n] = (f32x4){0.f, 0.f, 0.f, 0.f};

    const int arow = tid >> 2;
    const int ac8 = (tid & 3) * 8;
    char* alds0 = (char*)Als + wave * 1024;
    char* blds0 = (char*)Bls + wave * 1024;
    const int fr = lane & 15, kq = (lane >> 4) * 8;

    for (int k0 = 0; k0 < K; k0 += 32) {
        const unsigned short* ga0 = A  + (size_t)(bm + arow) * K + k0 + ac8;
        const unsigned short* gb0 = BT + (size_t)(bn + arow) * K + k0 + ac8;
        GLL(ga0, alds0);
        GLL(ga0 + (size_t)64 * K, alds0 + 4096);
        GLL(gb0, blds0);
        GLL(gb0 + (size_t)64 * K, blds0 + 4096);
        __syncthreads();

        bf16x8 af[4], bfr[4];
        #pragma unroll
        for (int m = 0; m < 4; m++)
            af[m] = *(const bf16x8*)&Als[(wr + m * 16 + fr) * 32 + kq];
        #pragma unroll
        for (int n = 0; n < 4; n++)
            bfr[n] = *(const bf16x8*)&Bls[(wc + n * 16 + fr) * 32 + kq];
        #pragma unroll
        for (int m = 0; m < 4; m++)
            #pragma unroll
            for (int n = 0; n < 4; n++)
                acc[m][n] = __builtin_amdgcn_mfma_f32_16x16x32_bf16(
                    af[m], bfr[n], acc[m][n], 0, 0, 0);
        __syncthreads();
    }

    const int cr = (lane >> 4) * 4;
    const int ccol = lane & 15;
    #pragma unroll
    for (int m = 0; m < 4; m++) {
        const int row = bm + wr + m * 16 + cr;
        #pragma unroll
        for (int n = 0; n < 4; n++) {
            const int col = bn + wc + n * 16 + ccol;
            const float bv = bias[col];
            #pragma unroll
            for (int j2 = 0; j2 < 4; j2++) {
                float v = acc[m][n][j2] + bv;
                if (BF16_OUT)
                    ((unsigned short*)Cv)[(size_t)(row + j2) * N + col] = f2bf(v);
                else
                    ((float*)Cv)[(size_t)(row + j2) * N + col] = v;
            }
        }
    }
}

// Small-tile GEMM: 64x64 tile, 4 waves each 32x32 (2x2 acc), for N=1024
// projection (4x more blocks -> 4+ blocks/CU). Same 1D XCD-region swizzle.
template<int RX, int RY, int NBX, bool BF16_OUT>
__global__ __launch_bounds__(256) void gemm_bf16_s(
    const unsigned short* __restrict__ A,
    const unsigned short* __restrict__ BT,
    const float* __restrict__ bias,
    void* __restrict__ Cv, int M, int N, int K)
{
    const int flat = blockIdx.x;
    const int xcd = flat & 7;
    const int j = flat >> 3;
    const int bx = (xcd % (NBX / RX)) * RX + (j % RX);
    const int by = (xcd / (NBX / RX)) * RY + (j / RX);

    __shared__ unsigned short Als[64 * 32];
    __shared__ unsigned short Bls[64 * 32];
    const int tid = threadIdx.x;
    const int wave = tid >> 6, lane = tid & 63;
    const int bm = bx * 64, bn = by * 64;
    const int wr = (wave >> 1) * 32, wc = (wave & 1) * 32;

    f32x4 acc[2][2];
    #pragma unroll
    for (int m = 0; m < 2; m++)
        #pragma unroll
        for (int n = 0; n < 2; n++)
            acc[m][n] = (f32x4){0.f, 0.f, 0.f, 0.f};

    const int arow = tid >> 2;
    const int ac8 = (tid & 3) * 8;
    char* alds = (char*)Als + tid * 16;
    char* blds = (char*)Bls + tid * 16;
    const int fr = lane & 15, kq = (lane >> 4) * 8;

    for (int k0 = 0; k0 < K; k0 += 32) {
        GLL(A  + (size_t)(bm + arow) * K + k0 + ac8, alds);
        GLL(BT + (size_t)(bn + arow) * K + k0 + ac8, blds);
        __syncthreads();

        bf16x8 af[2], bfr[2];
        #pragma unroll
        for (int m = 0; m < 2; m++)
            af[m] = *(const bf16x8*)&Als[(wr + m * 16 + fr) * 32 + kq];
        #pragma unroll
        for (int n = 0; n < 2; n++)
            bfr[n] = *(const bf16x8*)&Bls[(wc + n * 16 + fr) * 32 + kq];
        #pragma unroll
        for (int m = 0; m < 2; m++)
            #pragma unroll
            for (int n = 0; n < 2; n++)
                acc[m][n] = __builtin_amdgcn_mfma_f32_16x16x32_bf16(
                    af[m], bfr[n], acc[m][n], 0, 0, 0);
        __syncthreads();
    }

    const int cr = (lane >> 4) * 4;
    const int ccol = lane & 15;
    #pragma unroll
    for (int m = 0; m < 2; m++) {
        const int row = bm + wr + m * 16 + cr;
        #pragma unroll
        for (int n = 0; n < 2; n++) {
            const int col = bn + wc + n * 16 + ccol;
            const float bv = bias[col];
            #pragma unroll
            for (int j2 = 0; j2 < 4; j2++) {
                float v = acc[m][n][j2] + bv;
                if (BF16_OUT)
                    ((unsigned short*)Cv)[(size_t)(row + j2) * N + col] = f2bf(v);
                else
                    ((float*)Cv)[(size_t)(row + j2) * N + col] = v;
            }
        }
    }
}

// MFMA flash attention (r6 inner loop). 4 waves x 16 q-rows = one 64-row
// q-tile per block; 1024 blocks = 4 blocks/CU (4 x 40KB LDS = 160KB exactly).
// Per-CU balance: qb(k,u) reflected map -> every CU's 4 resident blocks sum
// to 66 tile-units. Double-buffered K/V staging, one barrier per tile.
__global__ __launch_bounds__(256) void attn_mfma(
    const unsigned short* __restrict__ qkv,
    const unsigned short* __restrict__ vt,
    unsigned short* __restrict__ a_out)
{
    const int f = blockIdx.x;
    const int k_ = f >> 8;                 // 0..3
    const int u = (f >> 5) & 7;            // 0..7 (stable per CU)
    const int bh = f & 31;
    const int qb = (k_ & 1) ? (k_ * 8 + 7 - u) : (k_ * 8 + u);
    const int b = bh >> 4, h = bh & 15;
    const int tid = threadIdx.x;
    const int w = tid >> 6, lane = tid & 63;
    const int c = lane & 15, hh = lane >> 4;

    __shared__ unsigned short Kls[2 * 64 * 64];
    __shared__ unsigned short Vls[2 * 64 * 64];
    __shared__ unsigned short Pls[4][16 * 64];

    const float Cc = 0.18033688f;          // 0.125 * log2(e)

    // staging geometry: LDS byte o = tid*16 (+4096); row r = o>>7; swizzled src col
    const int o0 = tid * 16;
    const int r0 = o0 >> 7, sc0 = (o0 & 127) ^ ((r0 & 7) << 4);
    const int o1 = 4096 + tid * 16;
    const int r1 = o1 >> 7, sc1 = (o1 & 127) ^ ((r1 & 7) << 4);

    char* kld = (char*)Kls + w * 1024;
    char* vld = (char*)Vls + w * 1024;
    const char* gkbase = (const char*)(qkv + (size_t)b * SEQ * QKV_LD + NSTATE + h * HDIM);
    const char* gvbase = (const char*)(vt + (size_t)(b * NHEAD + h) * HDIM * SEQ);

    #define STAGE(kt_, buf_) do { \
        const char* gk = gkbase + (size_t)(kt_) * 64 * 6144; \
        const char* gv = gvbase + (size_t)(kt_) * 128; \
        char* kd = kld + (buf_) * 8192; \
        char* vd = vld + (buf_) * 8192; \
        GLL(gk + (size_t)r0 * 6144 + sc0, kd); \
        GLL(gk + (size_t)r1 * 6144 + sc1, kd + 4096); \
        GLL(gv + (size_t)r0 * 4096 + sc0, vd); \
        GLL(gv + (size_t)r1 * 4096 + sc1, vd + 4096); \
    } while (0)

    const size_t qrow = (size_t)(b * SEQ + qb * 64 + w * 16 + c);
    const unsigned short* qp = qkv + qrow * QKV_LD + h * HDIM;
    bf16x8 qf0 = *(const bf16x8*)(qp + hh * 8);
    bf16x8 qf1 = *(const bf16x8*)(qp + 32 + hh * 8);

    f32x4 acc_o[4];
    #pragma unroll
    for (int n = 0; n < 4; n++) acc_o[n] = (f32x4){0.f, 0.f, 0.f, 0.f};
    float m_run = -1e30f, l = 0.f;

    const int nkt = qb + 1;
    STAGE(0, 0);
    __syncthreads();

    for (int kt = 0; kt < nkt; kt++) {
        const int cur = kt & 1;
        if (kt + 1 < nkt) STAGE(kt + 1, cur ^ 1);

        const char* kb = (const char*)Kls + cur * 8192;
        const char* vb = (const char*)Vls + cur * 8192;

        // QK^T (swapped): sacc[m] cols=q(c), rows=keys m*16 + hh*4 + j
        f32x4 sacc[4];
        __builtin_amdgcn_s_setprio(1);
        #pragma unroll
        for (int m = 0; m < 4; m++) {
            const int row = m * 16 + c;
            const int sw = (row & 7) << 4;
            bf16x8 kf0 = *(const bf16x8*)(kb + row * 128 + ((hh * 16) ^ sw));
            bf16x8 kf1 = *(const bf16x8*)(kb + row * 128 + ((64 + hh * 16) ^ sw));
            f32x4 z = (f32x4){0.f, 0.f, 0.f, 0.f};
            z = __builtin_amdgcn_mfma_f32_16x16x32_bf16(kf0, qf0, z, 0, 0, 0);
            sacc[m] = __builtin_amdgcn_mfma_f32_16x16x32_bf16(kf1, qf1, z, 0, 0, 0);
        }
        __builtin_amdgcn_s_setprio(0);

        // softmax on raw scores; scale folded into exp2 constant
        const bool diag = (kt == qb);
        float s[16];
        #pragma unroll
        for (int m = 0; m < 4; m++)
            #pragma unroll
            for (int j = 0; j < 4; j++) {
                float sv = sacc[m][j];
                if (diag) {
                    int klocal = m * 16 + hh * 4 + j;
                    if (klocal > w * 16 + c) sv = -1e30f;
                }
                s[m * 4 + j] = sv;
            }
        // tree max over 16
        float x0 = fmaxf(s[0], s[1]),  x1 = fmaxf(s[2], s[3]);
        float x2 = fmaxf(s[4], s[5]),  x3 = fmaxf(s[6], s[7]);
        float x4 = fmaxf(s[8], s[9]),  x5 = fmaxf(s[10], s[11]);
        float x6 = fmaxf(s[12], s[13]), x7 = fmaxf(s[14], s[15]);
        float y0 = fmaxf(x0, x1), y1 = fmaxf(x2, x3);
        float y2 = fmaxf(x4, x5), y3 = fmaxf(x6, x7);
        float pmax = fmaxf(fmaxf(y0, y1), fmaxf(y2, y3));
        pmax = fmaxf(pmax, __shfl_xor(pmax, 16));
        pmax = fmaxf(pmax, __shfl_xor(pmax, 32));

        // defer-max: rescale only if some row's max grew by > 64 raw (=8 scaled)
        if (!__all(pmax <= m_run + 64.0f)) {
            const float mnew = fmaxf(m_run, pmax);
            const float alpha = exp2f((m_run - mnew) * Cc);
            m_run = mnew;
            l *= alpha;
            const float a0 = __shfl(alpha, hh * 4 + 0);
            const float a1 = __shfl(alpha, hh * 4 + 1);
            const float a2 = __shfl(alpha, hh * 4 + 2);
            const float a3 = __shfl(alpha, hh * 4 + 3);
            #pragma unroll
            for (int n = 0; n < 4; n++) {
                acc_o[n][0] *= a0; acc_o[n][1] *= a1;
                acc_o[n][2] *= a2; acc_o[n][3] *= a3;
            }
        }
        const float mc = m_run * Cc;
        float p[16];
        #pragma unroll
        for (int i = 0; i < 16; i++)
            p[i] = exp2f(fmaf(s[i], Cc, -mc));
        // tree sum into l
        {
            float a0 = p[0] + p[1],  a1 = p[2] + p[3];
            float a2 = p[4] + p[5],  a3 = p[6] + p[7];
            float a4 = p[8] + p[9],  a5 = p[10] + p[11];
            float a6 = p[12] + p[13], a7 = p[14] + p[15];
            float b0 = a0 + a1, b1 = a2 + a3, b2 = a4 + a5, b3 = a6 + a7;
            l += (b0 + b1) + (b2 + b3);
        }

        // pack P -> bf16 via v_cvt_pk_bf16_f32, per-wave swizzled LDS
        {
            char* pb = (char*)&Pls[w][0] + c * 128;
            const int swp = (c & 7) << 4;
            #pragma unroll
            for (int m = 0; m < 4; m++) {
                uint2 u2;
                u2.x = cvtpk_bf16(p[m * 4 + 0], p[m * 4 + 1]);
                u2.y = cvtpk_bf16(p[m * 4 + 2], p[m * 4 + 3]);
                *(uint2*)(pb + ((m * 32 + hh * 8) ^ swp)) = u2;
            }
        }

        // PV: out[q][d], A = P, B = Vt
        {
            const char* pb = (const char*)&Pls[w][0] + c * 128;
            const int swp = (c & 7) << 4;
            bf16x8 pf0 = *(const bf16x8*)(pb + ((hh * 16) ^ swp));
            bf16x8 pf1 = *(const bf16x8*)(pb + ((64 + hh * 16) ^ swp));
            __builtin_amdgcn_s_setprio(1);
            #pragma unroll
            for (int n = 0; n < 4; n++) {
                const int row = n * 16 + c;
                const int sw = (row & 7) << 4;
                bf16x8 vf0 = *(const bf16x8*)(vb + row * 128 + ((hh * 16) ^ sw));
                bf16x8 vf1 = *(const bf16x8*)(vb + row * 128 + ((64 + hh * 16) ^ sw));
                acc_o[n] = __builtin_amdgcn_mfma_f32_16x16x32_bf16(pf0, vf0, acc_o[n], 0, 0, 0);
                acc_o[n] = __builtin_amdgcn_mfma_f32_16x16x32_bf16(pf1, vf1, acc_o[n], 0, 0, 0);
            }
            __builtin_amdgcn_s_setprio(0);
        }
        __syncthreads();
    }
    #undef STAGE

    // final normalization + store
    l += __shfl_xor(l, 16);
    l += __shfl_xor(l, 32);
    const float linv = 1.f / l;
    const float li0 = __shfl(linv, hh * 4 + 0);
    const float li1 = __shfl(linv, hh * 4 + 1);
    const float li2 = __shfl(linv, hh * 4 + 2);
    const float li3 = __shfl(linv, hh * 4 + 3);
    const size_t orow0 = (size_t)(b * SEQ + qb * 64 + w * 16 + hh * 4);
    #pragma unroll
    for (int n = 0; n < 4; n++) {
        const int col = h * HDIM + n * 16 + c;
        a_out[(orow0 + 0) * NSTATE + col] = f2bf(acc_o[n][0] * li0);
        a_out[(orow0 + 1) * NSTATE + col] = f2bf(acc_o[n][1] * li1);
        a_out[(orow0 + 2) * NSTATE + col] = f2bf(acc_o[n][2] * li2);
        a_out[(orow0 + 3) * NSTATE + col] = f2bf(acc_o[n][3] * li3);
    }
}

extern "C" void kernel_launch(void* const* d_in, const int* in_sizes, int n_in,
                              void* d_out, int out_size, void* d_ws, size_t ws_size,
                              hipStream_t stream)
{
    const float* x   = (const float*)d_in[0];
    const float* w_c = (const float*)d_in[1];
    const float* b_c = (const float*)d_in[2];
    const float* w_p = (const float*)d_in[3];
    const float* b_p = (const float*)d_in[4];
    float* out = (float*)d_out;

    const int M = BATCH * SEQ;   // 4096

    char* ws = (char*)d_ws;
    unsigned short* qkvbf = (unsigned short*)ws;                          // 25165824 B
    unsigned short* vt    = (unsigned short*)(ws + 25165824);             //  8388608 B
    unsigned short* xbf   = (unsigned short*)(ws + 25165824 + 8388608);   //  8388608 B (reused as attn_out)
    unsigned short* wcT   = (unsigned short*)(ws + 25165824 + 2*8388608); //  6291456 B
    unsigned short* wpT   = (unsigned short*)(ws + 25165824 + 2*8388608 + 6291456); // 2097152 B

    // fused prep: cast x + transpose-cast w_c, w_p
    prep_kernel<<<5120, 256, 0, stream>>>(x, w_c, w_p, xbf, wcT, wpT);

    // 1) QKV projection -> bf16 qkv   (grid 32x24 = 768, XCD regions 8x12)
    gemm_bf16<8, 12, 32, true><<<768, 256, 0, stream>>>(
        xbf, wcT, b_c, qkvbf, M, 3 * NSTATE, NX);

    // 1b) transpose V -> vt
    vtrans_kernel<<<dim3(SEQ / 64, BATCH * NHEAD), 256, 0, stream>>>(qkvbf, vt);

    // 2) MFMA flash attention (1024 one-tile blocks, 4 blocks/CU, balanced map)
    attn_mfma<<<1024, 256, 0, stream>>>(qkvbf, vt, xbf);

    // 3) output projection -> fp32 d_out  (64x64 tiles, grid 64x16 = 1024,
    //    XCD regions 16x8)
    gemm_bf16_s<16, 8, 64, false><<<1024, 256, 0, stream>>>(
        xbf, wpT, b_p, out, M, NSTATE, NX);
}